// Round 5
// baseline (611.796 us; speedup 1.0000x reference)
//
#include <hip/hip_runtime.h>

#define Hh 160
#define Ww 400
#define Cc 256
#define HW 64000
#define PITCH 401            // padded row stride in pixels (shared zero separator col)
#define XBASE 402            // pixel slot index of (x=0, y=0)
#define XT_PX 64963          // slots 0 .. (402 + 160*401 + 400)

typedef unsigned short u16;
typedef unsigned int   u32;
typedef __attribute__((ext_vector_type(8))) short short8;
typedef __attribute__((ext_vector_type(4))) float f32x4;

// Wa2: weights pre-arranged in MFMA A-fragment order (layout UNCHANGED).
// u16 index = (hm*72 + s)*4096 + mi8*512 + lane*8, hm = head*2+mt, s = cib*9+tap.
// element j of lane (q*16+n16): A[m = mt*128 + mi8*16 + n16][ci = cib*32 + q*8 + j][tap]
#define WA2_U16   (8*72*8*512)                 // 2,359,296 u16 = 4,718,592 B
// xt: bf16 image, cib-sliced pixel-major: [cib 8][slot XT_PX][32ch] (64 B per slot-slice)
#define XT_BYTES  ((size_t)8 * XT_PX * 64)     // 33,261,056 B
#define BSLICE    ((size_t)XT_PX * 64)         // bytes per cib slice
#define WS_NEED   ((size_t)WA2_U16 * 2 + XT_BYTES)   // 37,979,648 B

__device__ __forceinline__ u16 f2b(float v) {
    const u32 u = __float_as_uint(v);
    return (u16)((u + 0x7FFFu + ((u >> 16) & 1u)) >> 16);
}
__device__ __forceinline__ float sigclip(float v) {
    const float s = 1.0f / (1.0f + expf(-v));
    return fminf(fmaxf(s, 1e-4f), 1.0f - 1e-4f);
}
__device__ __forceinline__ void gload_lds16(const void* g, void* l) {
    __builtin_amdgcn_global_load_lds(
        (const __attribute__((address_space(1))) unsigned int*)g,
        (__attribute__((address_space(3))) unsigned int*)l, 16, 0, 0);
}

// ---------------------------------------------------------------------------
// Prep 1: weights -> MFMA fragment-ordered image (one block per (head,s)).
// ---------------------------------------------------------------------------
__global__ __launch_bounds__(256) void prep_weights(
    const float* __restrict__ w0, const float* __restrict__ w1p,
    const float* __restrict__ w2p, const float* __restrict__ w3p,
    u16* __restrict__ Wa2)
{
    const int blk  = blockIdx.x;           // head*72 + s
    const int head = blk / 72;
    const int s    = blk - head * 72;
    const int cib  = s / 9;
    const int tap  = s - cib * 9;
    const float* w = head == 0 ? w0 : head == 1 ? w1p : head == 2 ? w2p : w3p;

    const int t    = threadIdx.x;          // (((mt*2+mblk)*4+mi)*16 + n16)
    const int n16  = t & 15;
    const int mi   = (t >> 4) & 3;
    const int mblk = (t >> 6) & 1;
    const int mt   = t >> 7;
    const int m    = mt * 128 + mblk * 64 + mi * 16 + n16;
    const int hm   = head * 2 + mt;

    uint4* dst4 = (uint4*)Wa2 +
        ((size_t)((hm * 72 + s) * 2 + mblk) * 4 + mi) * 64 + n16;
    #pragma unroll
    for (int qq = 0; qq < 4; ++qq) {
        u16 tmp[8];
        #pragma unroll
        for (int j = 0; j < 8; ++j) {
            const int ci = cib * 32 + qq * 8 + j;
            tmp[j] = f2b(w[(size_t)m * (Cc * 9) + (size_t)ci * 9 + tap]);
        }
        dst4[qq * 16] = *(const uint4*)tmp;
    }
}

// ---------------------------------------------------------------------------
// Prep 2: x (fp32 [ci][p]) -> xt (bf16 [cib][slot][32ch]), slot = 402+y*401+x.
// ---------------------------------------------------------------------------
__global__ __launch_bounds__(256) void prep_x(
    const float* __restrict__ x, uint4* __restrict__ xt4)
{
    const int xx = blockIdx.x * 256 + threadIdx.x;   // grid (2,160)
    const int y  = blockIdx.y;
    if (xx >= Ww) return;
    const int p  = y * Ww + xx;
    const size_t slot = (size_t)XBASE + (size_t)y * PITCH + xx;
    #pragma unroll
    for (int cib = 0; cib < 8; ++cib) {
        uint4* dst = xt4 + ((size_t)cib * XT_PX + slot) * 4;   // 64 B = 4 uint4
        #pragma unroll
        for (int v = 0; v < 4; ++v) {
            u32 tmp[4];
            #pragma unroll
            for (int j = 0; j < 4; ++j) {
                const int ci = cib * 32 + v * 8 + j * 2;
                tmp[j] = (u32)f2b(x[(size_t)ci * HW + p])
                       | ((u32)f2b(x[(size_t)(ci + 1) * HW + p]) << 16);
            }
            dst[v] = *(const uint4*)tmp;
        }
    }
}

// Prep 3: zero halo slots (row y=-1, separator column, row y=160) in all 8 cib
// slices. grid = 965 blocks x 64 threads; thread: cib = t>>3, j = t&7 (8B each).
__global__ __launch_bounds__(64) void prep_zero(unsigned long long* __restrict__ xt64)
{
    const int b = blockIdx.x;              // 402 + 161 + 402 = 965
    int slot;
    if (b < 402)       slot = b;
    else if (b < 563)  slot = (b - 401) * PITCH;
    else               slot = 64561 + (b - 563);
    const int cib = threadIdx.x >> 3, j = threadIdx.x & 7;
    xt64[((size_t)cib * XT_PX + slot) * 8 + j] = 0ull;
}

// ---------------------------------------------------------------------------
// MFMA conv (round-2 verified structure + narrow last x-tile).
// Block: 256 thr = 4 waves (mt x nblk); wave tile 128m x 64px; 2 blocks/CU.
// LDS-staged A (16KB/step dbuf) + B (25344B/cib dbuf, XOR-swizzled), plain
// __syncthreads per step. Blocks x=0..5 compute 4 nj quadrants (px 0..383);
// block x==6 keeps the x0=336 clamp for staging/addressing but computes ONLY
// nj=3 (px 384..399): no duplicate output work, and the 320 light blocks
// backfill the scheduling tail (2240 blocks on 512 slots was 4.375 rounds ->
// makespan 5 rounds; mixed durations pack to ~4.4).
// ---------------------------------------------------------------------------
__global__ __launch_bounds__(256, 2) void conv_mfma(
    const u16* __restrict__ Wa2, const u16* __restrict__ xt,
    const float* __restrict__ b1_0, const float* __restrict__ b1_1,
    const float* __restrict__ b1_2, const float* __restrict__ b1_3,
    const float* __restrict__ w2_0, const float* __restrict__ w2_1,
    const float* __restrict__ w2_2, const float* __restrict__ w2_3,
    const float* __restrict__ b2_0, const float* __restrict__ b2_1,
    const float* __restrict__ b2_2, const float* __restrict__ b2_3,
    float* __restrict__ out)
{
    __shared__ __align__(16) u16 Ab[2][8192];   // 32 KB: [par][mt*4096+mi8*512+lane*8]
    __shared__ __align__(16) u16 Bb[2][12672];  // 50688 B: [par][row*4224 + ...]
    __shared__ float Red[128][2][8];            // 8 KB

    const int t    = threadIdx.x;
    const int lane = t & 63, wv = t >> 6;
    const int q    = lane >> 4, n16 = lane & 15;
    const bool nar = (blockIdx.x == 6);          // narrow last tile
    const int x0   = nar ? (Ww - 64) : blockIdx.x * 64;   // clamp keeps staging legal
    const int y0   = blockIdx.y * 2;
    const int head = blockIdx.z;              // 4 heads
    const int nblk = wv & 1;                  // row within the 2-row tile
    const int mt   = wv >> 1;                 // channel half

    // --- A staging source: wave wv copies u16 range [wv*2048,(wv+1)*2048) of the
    //     16KB step image, which equals (mt=wv>>1, half=wv&1) of Wa2's step block.
    const u16* asrc0 = Wa2 + (size_t)(head * 2 + mt) * (72 * 4096)
                          + (size_t)(wv & 1) * 2048 + (size_t)lane * 8;
    // --- B staging: wave wv stages row wv. Per-lane pre-swizzled source offsets.
    const int u = lane >> 2;
    const int swz_main = ((lane & 3) ^ ((lane >> 3) & 3)) * 16 + u * 64;        // + i*1024
    const int swz_tail = ((lane & 3) ^ ((1 + (lane >> 3)) & 3)) * 16 + (50 + u) * 64;
    const char* xtb = (const char*)xt;
    const size_t brow_slot = (size_t)(y0 - 1 + wv) * PITCH + (x0 - 1) + XBASE;

    // --- read-side B offsets (bytes within one Bb buffer, before row term)
    int boff[4][3];
    #pragma unroll
    for (int nj = 0; nj < 4; ++nj)
        #pragma unroll
        for (int kx = 0; kx < 3; ++kx) {
            const int pxi = nj * 16 + n16 + kx;
            boff[nj][kx] = pxi * 64 + ((q ^ ((pxi >> 1) & 3)) * 16);
        }

    f32x4 acc[8][4];
    #pragma unroll
    for (int mi = 0; mi < 8; ++mi)
        #pragma unroll
        for (int nj = 0; nj < 4; ++nj) {
            f32x4 z = {0.f, 0.f, 0.f, 0.f};
            acc[mi][nj] = z;
        }

    // prologue staging
    {   // A step 0 -> Ab[0]
        u16* adst = &Ab[0][wv * 2048];
        #pragma unroll
        for (int i = 0; i < 4; ++i)
            gload_lds16(asrc0 + i * 512, adst + i * 512);
        // B cib 0 -> Bb[0]
        const char* src = xtb + brow_slot * 64;
        u16* bdst = &Bb[0][wv * 2112];
        #pragma unroll
        for (int i = 0; i < 4; ++i)
            gload_lds16(src + i * 1024 + swz_main, bdst + i * 512);
        gload_lds16(src + swz_tail, bdst + 1600);
    }
    __syncthreads();

    for (int cib = 0; cib < 8; ++cib) {
        const int cpar = cib & 1;
        #pragma unroll
        for (int tap = 0; tap < 9; ++tap) {
            const int par = cpar ^ (tap & 1);
            // ---- issue next-step staging first (overlaps with this step's compute)
            if (tap < 8 || cib < 7) {
                const int s_next = cib * 9 + tap + 1;
                const u16* src = asrc0 + (size_t)s_next * 4096;
                u16* adst = &Ab[par ^ 1][wv * 2048];
                #pragma unroll
                for (int i = 0; i < 4; ++i)
                    gload_lds16(src + i * 512, adst + i * 512);
            }
            if (tap == 4 && cib < 7) {
                const char* src = xtb + ((size_t)(cib + 1) * XT_PX + brow_slot) * 64;
                u16* bdst = &Bb[cpar ^ 1][wv * 2112];
                #pragma unroll
                for (int i = 0; i < 4; ++i)
                    gload_lds16(src + i * 1024 + swz_main, bdst + i * 512);
                gload_lds16(src + swz_tail, bdst + 1600);
            }
            // ---- compute on Ab[par], Bb[cpar]
            const int ky = tap / 3, kx = tap - ky * 3;     // compile-time
            const u16*  abuf = &Ab[par][mt * 4096];
            const char* bbuf = (const char*)(&Bb[0][0]) + cpar * 25344
                             + (nblk + ky) * 4224;
            if (!nar) {
                short8 b[4];
                #pragma unroll
                for (int nj = 0; nj < 4; ++nj)
                    b[nj] = *(const short8*)(bbuf + boff[nj][kx]);
                #pragma unroll
                for (int mi = 0; mi < 8; ++mi) {
                    const short8 a = *(const short8*)(abuf + mi * 512 + lane * 8);
                    #pragma unroll
                    for (int nj = 0; nj < 4; ++nj)
                        acc[mi][nj] = __builtin_amdgcn_mfma_f32_16x16x32_bf16(
                            a, b[nj], acc[mi][nj], 0, 0, 0);
                }
            } else {
                // narrow: only quadrant nj=3 (px 384..399 of the row)
                const short8 b3 = *(const short8*)(bbuf + boff[3][kx]);
                #pragma unroll
                for (int mi = 0; mi < 8; ++mi) {
                    const short8 a = *(const short8*)(abuf + mi * 512 + lane * 8);
                    acc[mi][3] = __builtin_amdgcn_mfma_f32_16x16x32_bf16(
                        a, b3, acc[mi][3], 0, 0, 0);
                }
            }
            __syncthreads();
        }
    }

    // --- epilogue: bias + ReLU + 1x1 partials, LDS reduce (single barrier)
    const float* b1 = head == 0 ? b1_0 : head == 1 ? b1_1 : head == 2 ? b1_2 : b1_3;
    const float* w2 = head == 0 ? w2_0 : head == 1 ? w2_1 : head == 2 ? w2_2 : w2_3;
    const float* b2 = head == 0 ? b2_0 : head == 1 ? b2_1 : head == 2 ? b2_2 : b2_3;
    const int cout   = (head < 2) ? 1 : 2;
    const int outoff = head == 0 ? 0 : head == 1 ? HW : head == 2 ? 2 * HW : 4 * HW;

    float p0[4] = {0.f, 0.f, 0.f, 0.f}, p1[4] = {0.f, 0.f, 0.f, 0.f};
    #pragma unroll
    for (int mi = 0; mi < 8; ++mi)
        #pragma unroll
        for (int r = 0; r < 4; ++r) {
            const int m = mt * 128 + mi * 16 + q * 4 + r;
            const float bb = b1[m], wc0 = w2[m];
            const float wc1 = (cout == 2) ? w2[Cc + m] : 0.0f;
            #pragma unroll
            for (int nj = 0; nj < 4; ++nj) {
                const float h = fmaxf(acc[mi][nj][r] + bb, 0.0f);
                p0[nj] = fmaf(wc0, h, p0[nj]);
                p1[nj] = fmaf(wc1, h, p1[nj]);
            }
        }

    #pragma unroll
    for (int nj = 0; nj < 4; ++nj) {
        const int n = nblk * 64 + nj * 16 + n16;
        Red[n][0][mt * 4 + q] = p0[nj];
        Red[n][1][mt * 4 + q] = p1[nj];
    }
    __syncthreads();

    // narrow block: only columns (t&63)>=48 carry valid sums (nj=3)
    if (t < cout * 128 && (!nar || (t & 63) >= 48)) {
        const int n = t & 127, c = t >> 7;
        float sv = b2[c];
        #pragma unroll
        for (int i = 0; i < 8; ++i) sv += Red[n][c][i];   // full 256-ch sum
        if (head < 2) sv = sigclip(sv);
        const int xg = x0 + (n & 63);
        const int yg = y0 + (n >> 6);
        out[outoff + c * HW + yg * Ww + xg] = sv;
    }
}

// ---------------------------------------------------------------------------
// Fallback conv (green, slow) if ws too small for the fast path.
// ---------------------------------------------------------------------------
__global__ __launch_bounds__(256) void conv_head_simple(
    const float* __restrict__ x,
    const float* __restrict__ w1, const float* __restrict__ b1,
    const float* __restrict__ w2, const float* __restrict__ b2,
    float* __restrict__ out, int outoff, int cout, int apply_sig)
{
    const int px = threadIdx.x & 63;
    const int g  = threadIdx.x >> 6;
    const int x0 = blockIdx.x * 64;
    const int y  = blockIdx.y;
    const int xg = x0 + px;
    __shared__ float RedS[4][64][2];

    bool valid[9]; int xoff[9];
    #pragma unroll
    for (int dy = 0; dy < 3; ++dy) {
        const int yy = y + dy - 1;
        #pragma unroll
        for (int dx = 0; dx < 3; ++dx) {
            const int xx = xg + dx - 1;
            const int k = dy * 3 + dx;
            valid[k] = (yy >= 0 && yy < Hh && xx >= 0 && xx < Ww);
            xoff[k]  = valid[k] ? (yy * Ww + xx) : 0;
        }
    }
    float hid[64];
    #pragma unroll
    for (int mi = 0; mi < 64; ++mi) hid[mi] = b1[g * 64 + mi];
    for (int ci = 0; ci < Cc; ++ci) {
        const float* xch = x + (size_t)ci * HW;
        float xv[9];
        #pragma unroll
        for (int k = 0; k < 9; ++k) xv[k] = valid[k] ? xch[xoff[k]] : 0.0f;
        const float* wci = w1 + ((size_t)(g * 64) * Cc + ci) * 9;
        #pragma unroll 8
        for (int mi = 0; mi < 64; ++mi) {
            const float* wr = wci + (size_t)mi * (Cc * 9);
            float h = hid[mi];
            #pragma unroll
            for (int k = 0; k < 9; ++k) h = fmaf(wr[k], xv[k], h);
            hid[mi] = h;
        }
    }
    float p0 = 0.f, p1 = 0.f;
    #pragma unroll 8
    for (int mi = 0; mi < 64; ++mi) {
        const int m = g * 64 + mi;
        const float h = fmaxf(hid[mi], 0.0f);
        p0 = fmaf(w2[m], h, p0);
        if (cout == 2) p1 = fmaf(w2[Cc + m], h, p1);
    }
    RedS[g][px][0] = p0; RedS[g][px][1] = p1;
    __syncthreads();
    if (g == 0 && xg < Ww)
        for (int c = 0; c < cout; ++c) {
            float sv = b2[c] + RedS[0][px][c] + RedS[1][px][c]
                             + RedS[2][px][c] + RedS[3][px][c];
            if (apply_sig) sv = sigclip(sv);
            out[outoff + c * HW + y * Ww + xg] = sv;
        }
}

// ---------------------------------------------------------------------------
// Decode (green): reads [HW,6HW), writes [6HW,14HW).
// ---------------------------------------------------------------------------
__global__ __launch_bounds__(256) void finalize_decode(float* __restrict__ out)
{
    const int i = blockIdx.x * 256 + threadIdx.x;
    if (i >= HW) return;
    const int h = i / Ww;
    const int w = i - h * Ww;

    const float k0 = out[HW + i];
    const float km = (w > 0)      ? out[HW + i - 1] : -1e30f;
    const float kp = (w < Ww - 1) ? out[HW + i + 1] : -1e30f;
    const float hmax = fmaxf(km, fmaxf(k0, kp));
    const float heat = (hmax == k0) ? k0 : 0.0f;

    const float off0 = out[2 * HW + i];
    const float off1 = out[3 * HW + i];
    const float reg0 = out[4 * HW + i];
    const float reg1 = out[5 * HW + i];
    const bool kmask = heat > 0.4f;

    out[6 * HW + i] = heat;
    out[7 * HW + w * Hh + h] = (off1 < 1.0f && kmask) ? 1.0f : 0.0f;
    out[8 * HW + 2 * i]      = (float)w + off0;
    out[8 * HW + 2 * i + 1]  = (float)h + off1;
    out[10 * HW + 2 * i]     = (float)w + reg0;
    out[10 * HW + 2 * i + 1] = (float)h + reg1;
    const float kb = kmask ? 1.0f : 0.0f;
    out[12 * HW + 2 * i]     = kb;
    out[12 * HW + 2 * i + 1] = kb;
}

// ---------------------------------------------------------------------------
extern "C" void kernel_launch(void* const* d_in, const int* in_sizes, int n_in,
                              void* d_out, int out_size, void* d_ws, size_t ws_size,
                              hipStream_t stream) {
    (void)in_sizes; (void)n_in; (void)out_size;
    const float* x = (const float*)d_in[0];
    float* out = (float*)d_out;

    if (ws_size >= WS_NEED) {
        u16* Wa2 = (u16*)d_ws;
        u16* xt  = Wa2 + WA2_U16;             // cib-sliced padded bf16 image

        prep_weights<<<dim3(288), 256, 0, stream>>>(
            (const float*)d_in[1], (const float*)d_in[5],
            (const float*)d_in[9], (const float*)d_in[13], Wa2);
        prep_x<<<dim3(2, 160), 256, 0, stream>>>(x, (uint4*)xt);
        prep_zero<<<dim3(965), 64, 0, stream>>>((unsigned long long*)xt);

        conv_mfma<<<dim3(7, 80, 4), 256, 0, stream>>>(
            Wa2, xt,
            (const float*)d_in[2],  (const float*)d_in[6],
            (const float*)d_in[10], (const float*)d_in[14],
            (const float*)d_in[3],  (const float*)d_in[7],
            (const float*)d_in[11], (const float*)d_in[15],
            (const float*)d_in[4],  (const float*)d_in[8],
            (const float*)d_in[12], (const float*)d_in[16],
            out);
    } else {
        const int outoffs[4] = {0, HW, 2 * HW, 4 * HW};
        const int couts[4]   = {1, 1, 2, 2};
        for (int hd = 0; hd < 4; ++hd)
            conv_head_simple<<<dim3(7, 160), 256, 0, stream>>>(
                x,
                (const float*)d_in[1 + 4 * hd], (const float*)d_in[2 + 4 * hd],
                (const float*)d_in[3 + 4 * hd], (const float*)d_in[4 + 4 * hd],
                out, outoffs[hd], couts[hd], (hd < 2) ? 1 : 0);
    }
    finalize_decode<<<dim3(250), 256, 0, stream>>>(out);
}

// Round 6
// 441.159 us; speedup vs baseline: 1.3868x; 1.3868x over previous
//
#include <hip/hip_runtime.h>

#define Hh 160
#define Ww 400
#define Cc 256
#define HW 64000
#define PITCH 401            // padded row stride in pixels (shared zero separator col)
#define XBASE 402            // pixel slot index of (x=0, y=0)
#define XT_PX 64963          // slots 0 .. (402 + 160*401 + 400)

typedef unsigned short u16;
typedef unsigned int   u32;
typedef __attribute__((ext_vector_type(8))) short short8;
typedef __attribute__((ext_vector_type(4))) float f32x4;

// Wa2: weights pre-arranged in MFMA A-fragment order (layout UNCHANGED).
// u16 index = (hm*72 + s)*4096 + mi8*512 + lane*8, hm = head*2+mt, s = cib*9+tap.
// element j of lane (q*16+n16): A[m = mt*128 + mi8*16 + n16][ci = cib*32 + q*8 + j][tap]
#define WA2_U16   (8*72*8*512)                 // 2,359,296 u16 = 4,718,592 B
// xt: bf16 image, cib-sliced pixel-major: [cib 8][slot XT_PX][32ch] (64 B per slot-slice)
#define XT_BYTES  ((size_t)8 * XT_PX * 64)     // 33,261,056 B
#define BSLICE    ((size_t)XT_PX * 64)         // bytes per cib slice
#define WS_NEED   ((size_t)WA2_U16 * 2 + XT_BYTES)   // 37,979,648 B

__device__ __forceinline__ u16 f2b(float v) {
    const u32 u = __float_as_uint(v);
    return (u16)((u + 0x7FFFu + ((u >> 16) & 1u)) >> 16);
}
__device__ __forceinline__ float sigclip(float v) {
    const float s = 1.0f / (1.0f + expf(-v));
    return fminf(fmaxf(s, 1e-4f), 1.0f - 1e-4f);
}
__device__ __forceinline__ void gload_lds16(const void* g, void* l) {
    __builtin_amdgcn_global_load_lds(
        (const __attribute__((address_space(1))) unsigned int*)g,
        (__attribute__((address_space(3))) unsigned int*)l, 16, 0, 0);
}

// ---------------------------------------------------------------------------
// Prep 1: weights -> MFMA fragment-ordered image (one block per (head,s)).
// ---------------------------------------------------------------------------
__global__ __launch_bounds__(256) void prep_weights(
    const float* __restrict__ w0, const float* __restrict__ w1p,
    const float* __restrict__ w2p, const float* __restrict__ w3p,
    u16* __restrict__ Wa2)
{
    const int blk  = blockIdx.x;           // head*72 + s
    const int head = blk / 72;
    const int s    = blk - head * 72;
    const int cib  = s / 9;
    const int tap  = s - cib * 9;
    const float* w = head == 0 ? w0 : head == 1 ? w1p : head == 2 ? w2p : w3p;

    const int t    = threadIdx.x;          // (((mt*2+mblk)*4+mi)*16 + n16)
    const int n16  = t & 15;
    const int mi   = (t >> 4) & 3;
    const int mblk = (t >> 6) & 1;
    const int mt   = t >> 7;
    const int m    = mt * 128 + mblk * 64 + mi * 16 + n16;
    const int hm   = head * 2 + mt;

    uint4* dst4 = (uint4*)Wa2 +
        ((size_t)((hm * 72 + s) * 2 + mblk) * 4 + mi) * 64 + n16;
    #pragma unroll
    for (int qq = 0; qq < 4; ++qq) {
        u16 tmp[8];
        #pragma unroll
        for (int j = 0; j < 8; ++j) {
            const int ci = cib * 32 + qq * 8 + j;
            tmp[j] = f2b(w[(size_t)m * (Cc * 9) + (size_t)ci * 9 + tap]);
        }
        dst4[qq * 16] = *(const uint4*)tmp;
    }
}

// ---------------------------------------------------------------------------
// Prep 2: x (fp32 [ci][p]) -> xt (bf16 [cib][slot][32ch]), slot = 402+y*401+x.
// ---------------------------------------------------------------------------
__global__ __launch_bounds__(256) void prep_x(
    const float* __restrict__ x, uint4* __restrict__ xt4)
{
    const int xx = blockIdx.x * 256 + threadIdx.x;   // grid (2,160)
    const int y  = blockIdx.y;
    if (xx >= Ww) return;
    const int p  = y * Ww + xx;
    const size_t slot = (size_t)XBASE + (size_t)y * PITCH + xx;
    #pragma unroll
    for (int cib = 0; cib < 8; ++cib) {
        uint4* dst = xt4 + ((size_t)cib * XT_PX + slot) * 4;   // 64 B = 4 uint4
        #pragma unroll
        for (int v = 0; v < 4; ++v) {
            u32 tmp[4];
            #pragma unroll
            for (int j = 0; j < 4; ++j) {
                const int ci = cib * 32 + v * 8 + j * 2;
                tmp[j] = (u32)f2b(x[(size_t)ci * HW + p])
                       | ((u32)f2b(x[(size_t)(ci + 1) * HW + p]) << 16);
            }
            dst[v] = *(const uint4*)tmp;
        }
    }
}

// Prep 3: zero halo slots (row y=-1, separator column, row y=160) in all 8 cib
// slices. grid = 965 blocks x 64 threads; thread: cib = t>>3, j = t&7 (8B each).
__global__ __launch_bounds__(64) void prep_zero(unsigned long long* __restrict__ xt64)
{
    const int b = blockIdx.x;              // 402 + 161 + 402 = 965
    int slot;
    if (b < 402)       slot = b;
    else if (b < 563)  slot = (b - 401) * PITCH;
    else               slot = 64561 + (b - 563);
    const int cib = threadIdx.x >> 3, j = threadIdx.x & 7;
    xt64[((size_t)cib * XT_PX + slot) * 8 + j] = 0ull;
}

// ---------------------------------------------------------------------------
// MFMA conv: EXACT round-2 structure (256 thr = 4 waves (mt x nblk), wave
// tile 128m x 64px, LDS 74752 B, 2 blocks/CU, plain __syncthreads) with the
// narrow last x-tile added as a TOP-LEVEL cloned K-loop: blocks x=0..5
// compute 4 nj quadrants (px 0..383); block x==6 keeps the x0=336 clamp for
// staging/addressing but its K-loop computes ONLY nj=3 (px 384..399) -- 8
// MFMAs/step instead of 32. Branch hoisted OUT of the hot loop so register
// allocation = max(paths) = full path (~128), and the LDS footprint is
// byte-identical to round 2. The 320 light blocks backfill the scheduling
// tail (2240 uniform blocks on 512 slots = 4.375 rounds -> makespan 5;
// 1920 full + 320 half-weight pack to ~4.3).
// ---------------------------------------------------------------------------
__global__ __launch_bounds__(256, 2) void conv_mfma(
    const u16* __restrict__ Wa2, const u16* __restrict__ xt,
    const float* __restrict__ b1_0, const float* __restrict__ b1_1,
    const float* __restrict__ b1_2, const float* __restrict__ b1_3,
    const float* __restrict__ w2_0, const float* __restrict__ w2_1,
    const float* __restrict__ w2_2, const float* __restrict__ w2_3,
    const float* __restrict__ b2_0, const float* __restrict__ b2_1,
    const float* __restrict__ b2_2, const float* __restrict__ b2_3,
    float* __restrict__ out)
{
    __shared__ __align__(16) u16 Ab[2][8192];   // 32 KB: [par][mt*4096+mi8*512+lane*8]
    __shared__ __align__(16) u16 Bb[2][8448];   // 33 KB: [par][row*2112 + chunk*8]
    __shared__ float Red[128][2][8];            // 8 KB

    const int t    = threadIdx.x;
    const int lane = t & 63, wv = t >> 6;
    const int q    = lane >> 4, n16 = lane & 15;
    const bool nar = (blockIdx.x == 6);          // narrow last tile
    const int x0   = nar ? (Ww - 64) : blockIdx.x * 64;   // clamp keeps staging legal
    const int y0   = blockIdx.y * 2;
    const int head = blockIdx.z;              // 4 heads
    const int nblk = wv & 1;                  // row within the 2-row tile
    const int mt   = wv >> 1;                 // channel half

    // --- A staging source: wave wv copies u16 range [wv*2048,(wv+1)*2048) of the
    //     16KB step image, which equals (mt=wv>>1, half=wv&1) of Wa2's step block.
    const u16* asrc0 = Wa2 + (size_t)(head * 2 + mt) * (72 * 4096)
                          + (size_t)(wv & 1) * 2048 + (size_t)lane * 8;
    // --- B staging: wave wv stages row wv. Per-lane pre-swizzled source offsets.
    const int u = lane >> 2;
    const int swz_main = ((lane & 3) ^ ((lane >> 3) & 3)) * 16 + u * 64;        // + i*1024
    const int swz_tail = ((lane & 3) ^ ((1 + (lane >> 3)) & 3)) * 16 + (50 + u) * 64;
    const char* xtb = (const char*)xt;
    const size_t brow_slot = (size_t)(y0 - 1 + wv) * PITCH + (x0 - 1) + XBASE;

    // --- read-side B offsets (bytes within one Bb buffer, before row term)
    int boff[4][3];
    #pragma unroll
    for (int nj = 0; nj < 4; ++nj)
        #pragma unroll
        for (int kx = 0; kx < 3; ++kx) {
            const int pxi = nj * 16 + n16 + kx;
            boff[nj][kx] = pxi * 64 + ((q ^ ((pxi >> 1) & 3)) * 16);
        }

    f32x4 acc[8][4];
    #pragma unroll
    for (int mi = 0; mi < 8; ++mi)
        #pragma unroll
        for (int nj = 0; nj < 4; ++nj) {
            f32x4 z = {0.f, 0.f, 0.f, 0.f};
            acc[mi][nj] = z;
        }

    // prologue staging
    {   // A step 0 -> Ab[0]
        u16* adst = &Ab[0][wv * 2048];
        #pragma unroll
        for (int i = 0; i < 4; ++i)
            gload_lds16(asrc0 + i * 512, adst + i * 512);
        // B cib 0 -> Bb[0]
        const char* src = xtb + brow_slot * 64;
        u16* bdst = &Bb[0][wv * 2112];
        #pragma unroll
        for (int i = 0; i < 4; ++i)
            gload_lds16(src + i * 1024 + swz_main, bdst + i * 512);
        gload_lds16(src + swz_tail, bdst + 1600);
    }
    __syncthreads();

    if (!nar) {
        // ================= FULL PATH (blocks x=0..5): round-2 verbatim ======
        for (int cib = 0; cib < 8; ++cib) {
            const int cpar = cib & 1;
            #pragma unroll
            for (int tap = 0; tap < 9; ++tap) {
                const int par = cpar ^ (tap & 1);
                if (tap < 8 || cib < 7) {
                    const int s_next = cib * 9 + tap + 1;
                    const u16* src = asrc0 + (size_t)s_next * 4096;
                    u16* adst = &Ab[par ^ 1][wv * 2048];
                    #pragma unroll
                    for (int i = 0; i < 4; ++i)
                        gload_lds16(src + i * 512, adst + i * 512);
                }
                if (tap == 4 && cib < 7) {
                    const char* src = xtb + ((size_t)(cib + 1) * XT_PX + brow_slot) * 64;
                    u16* bdst = &Bb[cpar ^ 1][wv * 2112];
                    #pragma unroll
                    for (int i = 0; i < 4; ++i)
                        gload_lds16(src + i * 1024 + swz_main, bdst + i * 512);
                    gload_lds16(src + swz_tail, bdst + 1600);
                }
                const int ky = tap / 3, kx = tap - ky * 3;     // compile-time
                const u16*  abuf = &Ab[par][mt * 4096];
                const char* bbuf = (const char*)(&Bb[0][0]) + cpar * 16896
                                 + (nblk + ky) * 4224;
                short8 b[4];
                #pragma unroll
                for (int nj = 0; nj < 4; ++nj)
                    b[nj] = *(const short8*)(bbuf + boff[nj][kx]);
                #pragma unroll
                for (int mi = 0; mi < 8; ++mi) {
                    const short8 a = *(const short8*)(abuf + mi * 512 + lane * 8);
                    #pragma unroll
                    for (int nj = 0; nj < 4; ++nj)
                        acc[mi][nj] = __builtin_amdgcn_mfma_f32_16x16x32_bf16(
                            a, b[nj], acc[mi][nj], 0, 0, 0);
                }
                __syncthreads();
            }
        }
    } else {
        // ================= NARROW PATH (block x==6): nj=3 only ==============
        for (int cib = 0; cib < 8; ++cib) {
            const int cpar = cib & 1;
            #pragma unroll
            for (int tap = 0; tap < 9; ++tap) {
                const int par = cpar ^ (tap & 1);
                if (tap < 8 || cib < 7) {
                    const int s_next = cib * 9 + tap + 1;
                    const u16* src = asrc0 + (size_t)s_next * 4096;
                    u16* adst = &Ab[par ^ 1][wv * 2048];
                    #pragma unroll
                    for (int i = 0; i < 4; ++i)
                        gload_lds16(src + i * 512, adst + i * 512);
                }
                if (tap == 4 && cib < 7) {
                    const char* src = xtb + ((size_t)(cib + 1) * XT_PX + brow_slot) * 64;
                    u16* bdst = &Bb[cpar ^ 1][wv * 2112];
                    #pragma unroll
                    for (int i = 0; i < 4; ++i)
                        gload_lds16(src + i * 1024 + swz_main, bdst + i * 512);
                    gload_lds16(src + swz_tail, bdst + 1600);
                }
                const int ky = tap / 3, kx = tap - ky * 3;     // compile-time
                const u16*  abuf = &Ab[par][mt * 4096];
                const char* bbuf = (const char*)(&Bb[0][0]) + cpar * 16896
                                 + (nblk + ky) * 4224;
                const short8 b3 = *(const short8*)(bbuf + boff[3][kx]);
                #pragma unroll
                for (int mi = 0; mi < 8; ++mi) {
                    const short8 a = *(const short8*)(abuf + mi * 512 + lane * 8);
                    acc[mi][3] = __builtin_amdgcn_mfma_f32_16x16x32_bf16(
                        a, b3, acc[mi][3], 0, 0, 0);
                }
                __syncthreads();
            }
        }
    }

    // --- epilogue: bias + ReLU + 1x1 partials, LDS reduce (single barrier)
    const float* b1 = head == 0 ? b1_0 : head == 1 ? b1_1 : head == 2 ? b1_2 : b1_3;
    const float* w2 = head == 0 ? w2_0 : head == 1 ? w2_1 : head == 2 ? w2_2 : w2_3;
    const float* b2 = head == 0 ? b2_0 : head == 1 ? b2_1 : head == 2 ? b2_2 : b2_3;
    const int cout   = (head < 2) ? 1 : 2;
    const int outoff = head == 0 ? 0 : head == 1 ? HW : head == 2 ? 2 * HW : 4 * HW;

    float p0[4] = {0.f, 0.f, 0.f, 0.f}, p1[4] = {0.f, 0.f, 0.f, 0.f};
    #pragma unroll
    for (int mi = 0; mi < 8; ++mi)
        #pragma unroll
        for (int r = 0; r < 4; ++r) {
            const int m = mt * 128 + mi * 16 + q * 4 + r;
            const float bb = b1[m], wc0 = w2[m];
            const float wc1 = (cout == 2) ? w2[Cc + m] : 0.0f;
            #pragma unroll
            for (int nj = 0; nj < 4; ++nj) {
                const float h = fmaxf(acc[mi][nj][r] + bb, 0.0f);
                p0[nj] = fmaf(wc0, h, p0[nj]);
                p1[nj] = fmaf(wc1, h, p1[nj]);
            }
        }

    #pragma unroll
    for (int nj = 0; nj < 4; ++nj) {
        const int n = nblk * 64 + nj * 16 + n16;
        Red[n][0][mt * 4 + q] = p0[nj];
        Red[n][1][mt * 4 + q] = p1[nj];
    }
    __syncthreads();

    // narrow block: only columns (t&63)>=48 carry valid sums (nj=3)
    if (t < cout * 128 && (!nar || (t & 63) >= 48)) {
        const int n = t & 127, c = t >> 7;
        float sv = b2[c];
        #pragma unroll
        for (int i = 0; i < 8; ++i) sv += Red[n][c][i];   // full 256-ch sum
        if (head < 2) sv = sigclip(sv);
        const int xg = x0 + (n & 63);
        const int yg = y0 + (n >> 6);
        out[outoff + c * HW + yg * Ww + xg] = sv;
    }
}

// ---------------------------------------------------------------------------
// Fallback conv (green, slow) if ws too small for the fast path.
// ---------------------------------------------------------------------------
__global__ __launch_bounds__(256) void conv_head_simple(
    const float* __restrict__ x,
    const float* __restrict__ w1, const float* __restrict__ b1,
    const float* __restrict__ w2, const float* __restrict__ b2,
    float* __restrict__ out, int outoff, int cout, int apply_sig)
{
    const int px = threadIdx.x & 63;
    const int g  = threadIdx.x >> 6;
    const int x0 = blockIdx.x * 64;
    const int y  = blockIdx.y;
    const int xg = x0 + px;
    __shared__ float RedS[4][64][2];

    bool valid[9]; int xoff[9];
    #pragma unroll
    for (int dy = 0; dy < 3; ++dy) {
        const int yy = y + dy - 1;
        #pragma unroll
        for (int dx = 0; dx < 3; ++dx) {
            const int xx = xg + dx - 1;
            const int k = dy * 3 + dx;
            valid[k] = (yy >= 0 && yy < Hh && xx >= 0 && xx < Ww);
            xoff[k]  = valid[k] ? (yy * Ww + xx) : 0;
        }
    }
    float hid[64];
    #pragma unroll
    for (int mi = 0; mi < 64; ++mi) hid[mi] = b1[g * 64 + mi];
    for (int ci = 0; ci < Cc; ++ci) {
        const float* xch = x + (size_t)ci * HW;
        float xv[9];
        #pragma unroll
        for (int k = 0; k < 9; ++k) xv[k] = valid[k] ? xch[xoff[k]] : 0.0f;
        const float* wci = w1 + ((size_t)(g * 64) * Cc + ci) * 9;
        #pragma unroll 8
        for (int mi = 0; mi < 64; ++mi) {
            const float* wr = wci + (size_t)mi * (Cc * 9);
            float h = hid[mi];
            #pragma unroll
            for (int k = 0; k < 9; ++k) h = fmaf(wr[k], xv[k], h);
            hid[mi] = h;
        }
    }
    float p0 = 0.f, p1 = 0.f;
    #pragma unroll 8
    for (int mi = 0; mi < 64; ++mi) {
        const int m = g * 64 + mi;
        const float h = fmaxf(hid[mi], 0.0f);
        p0 = fmaf(w2[m], h, p0);
        if (cout == 2) p1 = fmaf(w2[Cc + m], h, p1);
    }
    RedS[g][px][0] = p0; RedS[g][px][1] = p1;
    __syncthreads();
    if (g == 0 && xg < Ww)
        for (int c = 0; c < cout; ++c) {
            float sv = b2[c] + RedS[0][px][c] + RedS[1][px][c]
                             + RedS[2][px][c] + RedS[3][px][c];
            if (apply_sig) sv = sigclip(sv);
            out[outoff + c * HW + y * Ww + xg] = sv;
        }
}

// ---------------------------------------------------------------------------
// Decode (green): reads [HW,6HW), writes [6HW,14HW).
// ---------------------------------------------------------------------------
__global__ __launch_bounds__(256) void finalize_decode(float* __restrict__ out)
{
    const int i = blockIdx.x * 256 + threadIdx.x;
    if (i >= HW) return;
    const int h = i / Ww;
    const int w = i - h * Ww;

    const float k0 = out[HW + i];
    const float km = (w > 0)      ? out[HW + i - 1] : -1e30f;
    const float kp = (w < Ww - 1) ? out[HW + i + 1] : -1e30f;
    const float hmax = fmaxf(km, fmaxf(k0, kp));
    const float heat = (hmax == k0) ? k0 : 0.0f;

    const float off0 = out[2 * HW + i];
    const float off1 = out[3 * HW + i];
    const float reg0 = out[4 * HW + i];
    const float reg1 = out[5 * HW + i];
    const bool kmask = heat > 0.4f;

    out[6 * HW + i] = heat;
    out[7 * HW + w * Hh + h] = (off1 < 1.0f && kmask) ? 1.0f : 0.0f;
    out[8 * HW + 2 * i]      = (float)w + off0;
    out[8 * HW + 2 * i + 1]  = (float)h + off1;
    out[10 * HW + 2 * i]     = (float)w + reg0;
    out[10 * HW + 2 * i + 1] = (float)h + reg1;
    const float kb = kmask ? 1.0f : 0.0f;
    out[12 * HW + 2 * i]     = kb;
    out[12 * HW + 2 * i + 1] = kb;
}

// ---------------------------------------------------------------------------
extern "C" void kernel_launch(void* const* d_in, const int* in_sizes, int n_in,
                              void* d_out, int out_size, void* d_ws, size_t ws_size,
                              hipStream_t stream) {
    (void)in_sizes; (void)n_in; (void)out_size;
    const float* x = (const float*)d_in[0];
    float* out = (float*)d_out;

    if (ws_size >= WS_NEED) {
        u16* Wa2 = (u16*)d_ws;
        u16* xt  = Wa2 + WA2_U16;             // cib-sliced padded bf16 image

        prep_weights<<<dim3(288), 256, 0, stream>>>(
            (const float*)d_in[1], (const float*)d_in[5],
            (const float*)d_in[9], (const float*)d_in[13], Wa2);
        prep_x<<<dim3(2, 160), 256, 0, stream>>>(x, (uint4*)xt);
        prep_zero<<<dim3(965), 64, 0, stream>>>((unsigned long long*)xt);

        conv_mfma<<<dim3(7, 80, 4), 256, 0, stream>>>(
            Wa2, xt,
            (const float*)d_in[2],  (const float*)d_in[6],
            (const float*)d_in[10], (const float*)d_in[14],
            (const float*)d_in[3],  (const float*)d_in[7],
            (const float*)d_in[11], (const float*)d_in[15],
            (const float*)d_in[4],  (const float*)d_in[8],
            (const float*)d_in[12], (const float*)d_in[16],
            out);
    } else {
        const int outoffs[4] = {0, HW, 2 * HW, 4 * HW};
        const int couts[4]   = {1, 1, 2, 2};
        for (int hd = 0; hd < 4; ++hd)
            conv_head_simple<<<dim3(7, 160), 256, 0, stream>>>(
                x,
                (const float*)d_in[1 + 4 * hd], (const float*)d_in[2 + 4 * hd],
                (const float*)d_in[3 + 4 * hd], (const float*)d_in[4 + 4 * hd],
                out, outoffs[hd], couts[hd], (hd < 2) ? 1 : 0);
    }
    finalize_decode<<<dim3(250), 256, 0, stream>>>(out);
}

// Round 7
// 426.377 us; speedup vs baseline: 1.4349x; 1.0347x over previous
//
#include <hip/hip_runtime.h>

#define Hh 160
#define Ww 400
#define Cc 256
#define HW 64000
#define PITCH 401            // padded row stride in pixels (shared zero separator col)
#define XBASE 402            // pixel slot index of (x=0, y=0)
#define XT_PX 64963          // slots 0 .. (402 + 160*401 + 400)

typedef unsigned short u16;
typedef unsigned int   u32;
typedef __attribute__((ext_vector_type(8))) short short8;
typedef __attribute__((ext_vector_type(4))) float f32x4;

// Wa2: weights pre-arranged in MFMA A-fragment order (layout UNCHANGED).
// u16 index = (hm*72 + s)*4096 + mi8*512 + lane*8, hm = head*2+mt, s = cib*9+tap.
// element j of lane (q*16+n16): A[m = mt*128 + mi8*16 + n16][ci = cib*32 + q*8 + j][tap]
#define WA2_U16   (8*72*8*512)                 // 2,359,296 u16 = 4,718,592 B
// xt: bf16 image, cib-sliced pixel-major: [cib 8][slot XT_PX][32ch] (64 B per slot-slice)
#define XT_BYTES  ((size_t)8 * XT_PX * 64)     // 33,261,056 B
#define BSLICE    ((size_t)XT_PX * 64)         // bytes per cib slice
#define WS_NEED   ((size_t)WA2_U16 * 2 + XT_BYTES)   // 37,979,648 B

__device__ __forceinline__ u16 f2b(float v) {
    const u32 u = __float_as_uint(v);
    return (u16)((u + 0x7FFFu + ((u >> 16) & 1u)) >> 16);
}
__device__ __forceinline__ float sigclip(float v) {
    const float s = 1.0f / (1.0f + expf(-v));
    return fminf(fmaxf(s, 1e-4f), 1.0f - 1e-4f);
}
__device__ __forceinline__ void gload_lds16(const void* g, void* l) {
    __builtin_amdgcn_global_load_lds(
        (const __attribute__((address_space(1))) unsigned int*)g,
        (__attribute__((address_space(3))) unsigned int*)l, 16, 0, 0);
}

// ---------------------------------------------------------------------------
// Fused prep: one kernel, three block-range phases (co-scheduled, 3 launches
// total for the whole pipeline instead of 5).
//  b in [0,64):    weights -> Wa2 via coalesced float4 load + LDS transpose
//                  (replaces the scattered-VMEM prep_weights: old version read
//                  32 scalar floats/lane at 9216-B lane stride = 64 cache
//                  lines per load instr, latency-bound at ~1 wave/SIMD).
//                  Block = (head, mgrp): 16 weight rows m = mt*128+mi8*16+n16.
//  b in [64,384):  x (fp32 [ci][p]) -> xt (bf16 [cib][slot][32ch]) transpose.
//  b in [384,512): zero halo slots (row y=-1, separator col, row y=160).
// ---------------------------------------------------------------------------
__global__ __launch_bounds__(256) void prep_all(
    const float* __restrict__ w0, const float* __restrict__ w1p,
    const float* __restrict__ w2p, const float* __restrict__ w3p,
    const float* __restrict__ x,
    u16* __restrict__ Wa2, uint4* __restrict__ xt4)
{
    __shared__ u16 lds16[16 * 2308];   // 73,856 B; row stride 2308 u16:
                                       // 4616 B = 8B-aligned, banks ~4-way max
    const int b = blockIdx.x, t = threadIdx.x;

    if (b < 64) {
        // ---- weights transpose ----
        const int head = b >> 4, mgrp = b & 15;
        const int mt = mgrp >> 3, mi8 = mgrp & 7;
        const int hm = head * 2 + mt;
        const int m0 = mt * 128 + mi8 * 16;      // rows m0..m0+15
        const float* w = head == 0 ? w0 : head == 1 ? w1p : head == 2 ? w2p : w3p;
        const float4* src = (const float4*)(w + (size_t)m0 * (Cc * 9));
        // coalesced load of 16x2304 floats, convert bf16, stage in LDS
        #pragma unroll
        for (int k = 0; k < 36; ++k) {
            const int f4 = t + k * 256;          // 9216 float4 total
            const int ml = f4 / 576;             // 576 float4 per row
            const int c4 = f4 - ml * 576;
            const float4 v = src[f4];
            uint2 pk;
            pk.x = (u32)f2b(v.x) | ((u32)f2b(v.y) << 16);
            pk.y = (u32)f2b(v.z) | ((u32)f2b(v.w) << 16);
            *(uint2*)&lds16[ml * 2308 + c4 * 4] = pk;
        }
        __syncthreads();
        // emit fragment-ordered Wa2: per s, one 1KB contiguous chunk (coalesced)
        #pragma unroll
        for (int k = 0; k < 18; ++k) {
            const int g = t + k * 256;           // 4608 uint4 = 72 s x 64 lanes
            const int lane = g & 63, s = g >> 6;
            const int cib = s / 9, tap = s - cib * 9;
            const int q = lane >> 4, n16 = lane & 15;
            u16 tmp[8];
            #pragma unroll
            for (int j = 0; j < 8; ++j)
                tmp[j] = lds16[n16 * 2308 + (cib * 32 + q * 8 + j) * 9 + tap];
            *(uint4*)(Wa2 + ((size_t)(hm * 72 + s) * 8 + mi8) * 512 + lane * 8)
                = *(const uint4*)tmp;
        }
    } else if (b < 384) {
        // ---- x -> xt transpose ----
        const int bb = b - 64;
        const int xx = (bb & 1) * 256 + t;
        const int y  = bb >> 1;
        if (xx < Ww) {
            const int p = y * Ww + xx;
            const size_t slot = (size_t)XBASE + (size_t)y * PITCH + xx;
            #pragma unroll
            for (int cib = 0; cib < 8; ++cib) {
                uint4* dst = xt4 + ((size_t)cib * XT_PX + slot) * 4;
                #pragma unroll
                for (int v = 0; v < 4; ++v) {
                    u32 tmp[4];
                    #pragma unroll
                    for (int j = 0; j < 4; ++j) {
                        const int ci = cib * 32 + v * 8 + j * 2;
                        tmp[j] = (u32)f2b(x[(size_t)ci * HW + p])
                               | ((u32)f2b(x[(size_t)(ci + 1) * HW + p]) << 16);
                    }
                    dst[v] = *(const uint4*)tmp;
                }
            }
        }
    } else {
        // ---- halo zeroing: 965 slots x 8 cib x 64 B = 30,880 uint4 ----
        const int i = (b - 384) * 256 + t;
        if (i < 965 * 32) {
            const int slot_i = i >> 5, c = i & 31;
            int slot;
            if (slot_i < 402)      slot = slot_i;
            else if (slot_i < 563) slot = (slot_i - 401) * PITCH;
            else                   slot = 64561 + (slot_i - 563);
            const int cib = c >> 2, v = c & 3;
            const uint4 z = {0u, 0u, 0u, 0u};
            xt4[((size_t)cib * XT_PX + slot) * 4 + v] = z;
        }
    }
}

// ---------------------------------------------------------------------------
// MFMA conv: round-2 structure (256 thr = 4 waves (mt x nblk), wave tile
// 128m x 64px, LDS 74752 B, 2 blocks/CU, plain __syncthreads) with the
// narrow last x-tile as a TOP-LEVEL cloned K-loop (verified round 6:
// 315.9 us, MfmaUtil 43.1, 956 TF effective -- at the 2-barrier-structure
// ceiling; rounds 3/4 showed deeper in-block pipelining regresses here).
// ---------------------------------------------------------------------------
__global__ __launch_bounds__(256, 2) void conv_mfma(
    const u16* __restrict__ Wa2, const u16* __restrict__ xt,
    const float* __restrict__ b1_0, const float* __restrict__ b1_1,
    const float* __restrict__ b1_2, const float* __restrict__ b1_3,
    const float* __restrict__ w2_0, const float* __restrict__ w2_1,
    const float* __restrict__ w2_2, const float* __restrict__ w2_3,
    const float* __restrict__ b2_0, const float* __restrict__ b2_1,
    const float* __restrict__ b2_2, const float* __restrict__ b2_3,
    float* __restrict__ out)
{
    __shared__ __align__(16) u16 Ab[2][8192];   // 32 KB: [par][mt*4096+mi8*512+lane*8]
    __shared__ __align__(16) u16 Bb[2][8448];   // 33 KB: [par][row*2112 + chunk*8]
    __shared__ float Red[128][2][8];            // 8 KB

    const int t    = threadIdx.x;
    const int lane = t & 63, wv = t >> 6;
    const int q    = lane >> 4, n16 = lane & 15;
    const bool nar = (blockIdx.x == 6);          // narrow last tile
    const int x0   = nar ? (Ww - 64) : blockIdx.x * 64;   // clamp keeps staging legal
    const int y0   = blockIdx.y * 2;
    const int head = blockIdx.z;              // 4 heads
    const int nblk = wv & 1;                  // row within the 2-row tile
    const int mt   = wv >> 1;                 // channel half

    // --- A staging source: wave wv copies u16 range [wv*2048,(wv+1)*2048) of the
    //     16KB step image, which equals (mt=wv>>1, half=wv&1) of Wa2's step block.
    const u16* asrc0 = Wa2 + (size_t)(head * 2 + mt) * (72 * 4096)
                          + (size_t)(wv & 1) * 2048 + (size_t)lane * 8;
    // --- B staging: wave wv stages row wv. Per-lane pre-swizzled source offsets.
    const int u = lane >> 2;
    const int swz_main = ((lane & 3) ^ ((lane >> 3) & 3)) * 16 + u * 64;        // + i*1024
    const int swz_tail = ((lane & 3) ^ ((1 + (lane >> 3)) & 3)) * 16 + (50 + u) * 64;
    const char* xtb = (const char*)xt;
    const size_t brow_slot = (size_t)(y0 - 1 + wv) * PITCH + (x0 - 1) + XBASE;

    // --- read-side B offsets (bytes within one Bb buffer, before row term)
    int boff[4][3];
    #pragma unroll
    for (int nj = 0; nj < 4; ++nj)
        #pragma unroll
        for (int kx = 0; kx < 3; ++kx) {
            const int pxi = nj * 16 + n16 + kx;
            boff[nj][kx] = pxi * 64 + ((q ^ ((pxi >> 1) & 3)) * 16);
        }

    f32x4 acc[8][4];
    #pragma unroll
    for (int mi = 0; mi < 8; ++mi)
        #pragma unroll
        for (int nj = 0; nj < 4; ++nj) {
            f32x4 z = {0.f, 0.f, 0.f, 0.f};
            acc[mi][nj] = z;
        }

    // prologue staging
    {   // A step 0 -> Ab[0]
        u16* adst = &Ab[0][wv * 2048];
        #pragma unroll
        for (int i = 0; i < 4; ++i)
            gload_lds16(asrc0 + i * 512, adst + i * 512);
        // B cib 0 -> Bb[0]
        const char* src = xtb + brow_slot * 64;
        u16* bdst = &Bb[0][wv * 2112];
        #pragma unroll
        for (int i = 0; i < 4; ++i)
            gload_lds16(src + i * 1024 + swz_main, bdst + i * 512);
        gload_lds16(src + swz_tail, bdst + 1600);
    }
    __syncthreads();

    if (!nar) {
        // ================= FULL PATH (blocks x=0..5): round-2 verbatim ======
        for (int cib = 0; cib < 8; ++cib) {
            const int cpar = cib & 1;
            #pragma unroll
            for (int tap = 0; tap < 9; ++tap) {
                const int par = cpar ^ (tap & 1);
                if (tap < 8 || cib < 7) {
                    const int s_next = cib * 9 + tap + 1;
                    const u16* src = asrc0 + (size_t)s_next * 4096;
                    u16* adst = &Ab[par ^ 1][wv * 2048];
                    #pragma unroll
                    for (int i = 0; i < 4; ++i)
                        gload_lds16(src + i * 512, adst + i * 512);
                }
                if (tap == 4 && cib < 7) {
                    const char* src = xtb + ((size_t)(cib + 1) * XT_PX + brow_slot) * 64;
                    u16* bdst = &Bb[cpar ^ 1][wv * 2112];
                    #pragma unroll
                    for (int i = 0; i < 4; ++i)
                        gload_lds16(src + i * 1024 + swz_main, bdst + i * 512);
                    gload_lds16(src + swz_tail, bdst + 1600);
                }
                const int ky = tap / 3, kx = tap - ky * 3;     // compile-time
                const u16*  abuf = &Ab[par][mt * 4096];
                const char* bbuf = (const char*)(&Bb[0][0]) + cpar * 16896
                                 + (nblk + ky) * 4224;
                short8 b[4];
                #pragma unroll
                for (int nj = 0; nj < 4; ++nj)
                    b[nj] = *(const short8*)(bbuf + boff[nj][kx]);
                #pragma unroll
                for (int mi = 0; mi < 8; ++mi) {
                    const short8 a = *(const short8*)(abuf + mi * 512 + lane * 8);
                    #pragma unroll
                    for (int nj = 0; nj < 4; ++nj)
                        acc[mi][nj] = __builtin_amdgcn_mfma_f32_16x16x32_bf16(
                            a, b[nj], acc[mi][nj], 0, 0, 0);
                }
                __syncthreads();
            }
        }
    } else {
        // ================= NARROW PATH (block x==6): nj=3 only ==============
        for (int cib = 0; cib < 8; ++cib) {
            const int cpar = cib & 1;
            #pragma unroll
            for (int tap = 0; tap < 9; ++tap) {
                const int par = cpar ^ (tap & 1);
                if (tap < 8 || cib < 7) {
                    const int s_next = cib * 9 + tap + 1;
                    const u16* src = asrc0 + (size_t)s_next * 4096;
                    u16* adst = &Ab[par ^ 1][wv * 2048];
                    #pragma unroll
                    for (int i = 0; i < 4; ++i)
                        gload_lds16(src + i * 512, adst + i * 512);
                }
                if (tap == 4 && cib < 7) {
                    const char* src = xtb + ((size_t)(cib + 1) * XT_PX + brow_slot) * 64;
                    u16* bdst = &Bb[cpar ^ 1][wv * 2112];
                    #pragma unroll
                    for (int i = 0; i < 4; ++i)
                        gload_lds16(src + i * 1024 + swz_main, bdst + i * 512);
                    gload_lds16(src + swz_tail, bdst + 1600);
                }
                const int ky = tap / 3, kx = tap - ky * 3;     // compile-time
                const u16*  abuf = &Ab[par][mt * 4096];
                const char* bbuf = (const char*)(&Bb[0][0]) + cpar * 16896
                                 + (nblk + ky) * 4224;
                const short8 b3 = *(const short8*)(bbuf + boff[3][kx]);
                #pragma unroll
                for (int mi = 0; mi < 8; ++mi) {
                    const short8 a = *(const short8*)(abuf + mi * 512 + lane * 8);
                    acc[mi][3] = __builtin_amdgcn_mfma_f32_16x16x32_bf16(
                        a, b3, acc[mi][3], 0, 0, 0);
                }
                __syncthreads();
            }
        }
    }

    // --- epilogue: bias + ReLU + 1x1 partials, LDS reduce (single barrier)
    const float* b1 = head == 0 ? b1_0 : head == 1 ? b1_1 : head == 2 ? b1_2 : b1_3;
    const float* w2 = head == 0 ? w2_0 : head == 1 ? w2_1 : head == 2 ? w2_2 : w2_3;
    const float* b2 = head == 0 ? b2_0 : head == 1 ? b2_1 : head == 2 ? b2_2 : b2_3;
    const int cout   = (head < 2) ? 1 : 2;
    const int outoff = head == 0 ? 0 : head == 1 ? HW : head == 2 ? 2 * HW : 4 * HW;

    float p0[4] = {0.f, 0.f, 0.f, 0.f}, p1[4] = {0.f, 0.f, 0.f, 0.f};
    #pragma unroll
    for (int mi = 0; mi < 8; ++mi)
        #pragma unroll
        for (int r = 0; r < 4; ++r) {
            const int m = mt * 128 + mi * 16 + q * 4 + r;
            const float bb = b1[m], wc0 = w2[m];
            const float wc1 = (cout == 2) ? w2[Cc + m] : 0.0f;
            #pragma unroll
            for (int nj = 0; nj < 4; ++nj) {
                const float h = fmaxf(acc[mi][nj][r] + bb, 0.0f);
                p0[nj] = fmaf(wc0, h, p0[nj]);
                p1[nj] = fmaf(wc1, h, p1[nj]);
            }
        }

    #pragma unroll
    for (int nj = 0; nj < 4; ++nj) {
        const int n = nblk * 64 + nj * 16 + n16;
        Red[n][0][mt * 4 + q] = p0[nj];
        Red[n][1][mt * 4 + q] = p1[nj];
    }
    __syncthreads();

    // narrow block: only columns (t&63)>=48 carry valid sums (nj=3)
    if (t < cout * 128 && (!nar || (t & 63) >= 48)) {
        const int n = t & 127, c = t >> 7;
        float sv = b2[c];
        #pragma unroll
        for (int i = 0; i < 8; ++i) sv += Red[n][c][i];   // full 256-ch sum
        if (head < 2) sv = sigclip(sv);
        const int xg = x0 + (n & 63);
        const int yg = y0 + (n >> 6);
        out[outoff + c * HW + yg * Ww + xg] = sv;
    }
}

// ---------------------------------------------------------------------------
// Fallback conv (green, slow) if ws too small for the fast path.
// ---------------------------------------------------------------------------
__global__ __launch_bounds__(256) void conv_head_simple(
    const float* __restrict__ x,
    const float* __restrict__ w1, const float* __restrict__ b1,
    const float* __restrict__ w2, const float* __restrict__ b2,
    float* __restrict__ out, int outoff, int cout, int apply_sig)
{
    const int px = threadIdx.x & 63;
    const int g  = threadIdx.x >> 6;
    const int x0 = blockIdx.x * 64;
    const int y  = blockIdx.y;
    const int xg = x0 + px;
    __shared__ float RedS[4][64][2];

    bool valid[9]; int xoff[9];
    #pragma unroll
    for (int dy = 0; dy < 3; ++dy) {
        const int yy = y + dy - 1;
        #pragma unroll
        for (int dx = 0; dx < 3; ++dx) {
            const int xx = xg + dx - 1;
            const int k = dy * 3 + dx;
            valid[k] = (yy >= 0 && yy < Hh && xx >= 0 && xx < Ww);
            xoff[k]  = valid[k] ? (yy * Ww + xx) : 0;
        }
    }
    float hid[64];
    #pragma unroll
    for (int mi = 0; mi < 64; ++mi) hid[mi] = b1[g * 64 + mi];
    for (int ci = 0; ci < Cc; ++ci) {
        const float* xch = x + (size_t)ci * HW;
        float xv[9];
        #pragma unroll
        for (int k = 0; k < 9; ++k) xv[k] = valid[k] ? xch[xoff[k]] : 0.0f;
        const float* wci = w1 + ((size_t)(g * 64) * Cc + ci) * 9;
        #pragma unroll 8
        for (int mi = 0; mi < 64; ++mi) {
            const float* wr = wci + (size_t)mi * (Cc * 9);
            float h = hid[mi];
            #pragma unroll
            for (int k = 0; k < 9; ++k) h = fmaf(wr[k], xv[k], h);
            hid[mi] = h;
        }
    }
    float p0 = 0.f, p1 = 0.f;
    #pragma unroll 8
    for (int mi = 0; mi < 64; ++mi) {
        const int m = g * 64 + mi;
        const float h = fmaxf(hid[mi], 0.0f);
        p0 = fmaf(w2[m], h, p0);
        if (cout == 2) p1 = fmaf(w2[Cc + m], h, p1);
    }
    RedS[g][px][0] = p0; RedS[g][px][1] = p1;
    __syncthreads();
    if (g == 0 && xg < Ww)
        for (int c = 0; c < cout; ++c) {
            float sv = b2[c] + RedS[0][px][c] + RedS[1][px][c]
                             + RedS[2][px][c] + RedS[3][px][c];
            if (apply_sig) sv = sigclip(sv);
            out[outoff + c * HW + y * Ww + xg] = sv;
        }
}

// ---------------------------------------------------------------------------
// Decode (green): reads [HW,6HW), writes [6HW,14HW).
// ---------------------------------------------------------------------------
__global__ __launch_bounds__(256) void finalize_decode(float* __restrict__ out)
{
    const int i = blockIdx.x * 256 + threadIdx.x;
    if (i >= HW) return;
    const int h = i / Ww;
    const int w = i - h * Ww;

    const float k0 = out[HW + i];
    const float km = (w > 0)      ? out[HW + i - 1] : -1e30f;
    const float kp = (w < Ww - 1) ? out[HW + i + 1] : -1e30f;
    const float hmax = fmaxf(km, fmaxf(k0, kp));
    const float heat = (hmax == k0) ? k0 : 0.0f;

    const float off0 = out[2 * HW + i];
    const float off1 = out[3 * HW + i];
    const float reg0 = out[4 * HW + i];
    const float reg1 = out[5 * HW + i];
    const bool kmask = heat > 0.4f;

    out[6 * HW + i] = heat;
    out[7 * HW + w * Hh + h] = (off1 < 1.0f && kmask) ? 1.0f : 0.0f;
    out[8 * HW + 2 * i]      = (float)w + off0;
    out[8 * HW + 2 * i + 1]  = (float)h + off1;
    out[10 * HW + 2 * i]     = (float)w + reg0;
    out[10 * HW + 2 * i + 1] = (float)h + reg1;
    const float kb = kmask ? 1.0f : 0.0f;
    out[12 * HW + 2 * i]     = kb;
    out[12 * HW + 2 * i + 1] = kb;
}

// ---------------------------------------------------------------------------
extern "C" void kernel_launch(void* const* d_in, const int* in_sizes, int n_in,
                              void* d_out, int out_size, void* d_ws, size_t ws_size,
                              hipStream_t stream) {
    (void)in_sizes; (void)n_in; (void)out_size;
    const float* x = (const float*)d_in[0];
    float* out = (float*)d_out;

    if (ws_size >= WS_NEED) {
        u16* Wa2 = (u16*)d_ws;
        u16* xt  = Wa2 + WA2_U16;             // cib-sliced padded bf16 image

        prep_all<<<dim3(512), 256, 0, stream>>>(
            (const float*)d_in[1], (const float*)d_in[5],
            (const float*)d_in[9], (const float*)d_in[13],
            x, Wa2, (uint4*)xt);

        conv_mfma<<<dim3(7, 80, 4), 256, 0, stream>>>(
            Wa2, xt,
            (const float*)d_in[2],  (const float*)d_in[6],
            (const float*)d_in[10], (const float*)d_in[14],
            (const float*)d_in[3],  (const float*)d_in[7],
            (const float*)d_in[11], (const float*)d_in[15],
            (const float*)d_in[4],  (const float*)d_in[8],
            (const float*)d_in[12], (const float*)d_in[16],
            out);
    } else {
        const int outoffs[4] = {0, HW, 2 * HW, 4 * HW};
        const int couts[4]   = {1, 1, 2, 2};
        for (int hd = 0; hd < 4; ++hd)
            conv_head_simple<<<dim3(7, 160), 256, 0, stream>>>(
                x,
                (const float*)d_in[1 + 4 * hd], (const float*)d_in[2 + 4 * hd],
                (const float*)d_in[3 + 4 * hd], (const float*)d_in[4 + 4 * hd],
                out, outoffs[hd], couts[hd], (hd < 2) ? 1 : 0);
    }
    finalize_decode<<<dim3(250), 256, 0, stream>>>(out);
}